// Round 19
// baseline (743.107 us; speedup 1.0000x reference)
//
#include <hip/hip_runtime.h>
#include <stdint.h>

typedef unsigned short u16;
typedef unsigned int u32;
typedef __attribute__((ext_vector_type(4))) float f32x4;
typedef __attribute__((ext_vector_type(8))) short bf16x8;

#define NN 32768
#define EE 524288
#define DD 384
#define NREL 8
#define NGR 128
#define NCAT (NREL * DD)  // 3072
#define LHALF 1536        // half-lin row width (4 relations)

__device__ __forceinline__ float bf2f(u16 u) {
  union { u32 u; float f; } v; v.u = ((u32)u) << 16; return v.f;
}
__device__ __forceinline__ u16 f2bf(float f) {
  union { float f; u32 u; } v; v.f = f;
  u32 r = v.u + 0x7fffu + ((v.u >> 16) & 1u);
  return (u16)(r >> 16);
}
__device__ __forceinline__ float2 up2(u32 p) {
  return make_float2(bf2f((u16)(p & 0xffffu)), bf2f((u16)(p >> 16)));
}
__device__ __forceinline__ u32 pk2(float a, float b) {
  return (u32)f2bf(a) | ((u32)f2bf(b) << 16);
}
// async 16B global->LDS (LDS dest = wave-uniform base + lane*16)
__device__ __forceinline__ void gl16(const u16* g, char* s) {
  __builtin_amdgcn_global_load_lds(
      (const __attribute__((address_space(1))) unsigned int*)(const void*)g,
      (__attribute__((address_space(3))) unsigned int*)(void*)s, 16, 0, 0);
}
__device__ __forceinline__ float dot4(uint4 a, uint4 b) {
  float2 p, q; float acc;
  p = up2(a.x); q = up2(b.x); acc  = p.x * q.x + p.y * q.y;
  p = up2(a.y); q = up2(b.y); acc += p.x * q.x + p.y * q.y;
  p = up2(a.z); q = up2(b.z); acc += p.x * q.x + p.y * q.y;
  p = up2(a.w); q = up2(b.w); acc += p.x * q.x + p.y * q.y;
  return acc;
}

// ---- per-node: invn = 1/|x|, H = bf16(x) ; zero cur ----
__global__ __launch_bounds__(256) void k_invnorm(const float* __restrict__ x,
                                                 float* __restrict__ invn,
                                                 u16* __restrict__ h0,
                                                 int* __restrict__ cur) {
  const int gid = blockIdx.x * 256 + threadIdx.x;
  if (gid < NN) cur[gid] = 0;
  const int node = gid >> 6;
  const int l = threadIdx.x & 63;
  const float* row = x + (size_t)node * DD;
  float v[6];
  float s = 0.f;
#pragma unroll
  for (int j = 0; j < 6; ++j) { v[j] = row[l + 64 * j]; s += v[j] * v[j]; }
#pragma unroll
  for (int off = 32; off > 0; off >>= 1) s += __shfl_xor(s, off, 64);
  if (l == 0) invn[node] = rsqrtf(s);
  u16* hr = h0 + (size_t)node * DD;
#pragma unroll
  for (int j = 0; j < 6; ++j) hr[l + 64 * j] = f2bf(v[j]);
}

// ---- weight transpose + bf16 convert ----
// W3T[r*384+n][k] (3072 x 384) = W_rel[r][k][n]   (B^T for the lin-GEMM)
// W2T[j][k]       (384 x 768)  = k<384 ? W_mp[k][j] : W_self[k-384][j]
__global__ void k_prepW(const float* __restrict__ Wrel, const float* __restrict__ Wmp,
                        const float* __restrict__ Wself,
                        u16* __restrict__ W3T, u16* __restrict__ W2T) {
  const int i = blockIdx.x * 256 + threadIdx.x;
  const int total1 = NCAT * DD;
  const int total2 = DD * 768;
  if (i < total1) {
    const int ncat = i / DD, k = i % DD;
    const int r = ncat / DD, n = ncat % DD;
    W3T[i] = f2bf(Wrel[(size_t)r * DD * DD + (size_t)k * DD + n]);
  } else if (i < total1 + total2) {
    const int ii = i - total1;
    const int j = ii / 768, k = ii % 768;
    const float v = (k < DD) ? Wmp[k * DD + j] : Wself[(k - DD) * DD + j];
    W2T[ii] = f2bf(v);
  }
}

// ---- per-edge weight: 16 lanes/edge + fused hist ----
__global__ __launch_bounds__(256) void k_cos(const u16* __restrict__ H,
                                             const float* __restrict__ invn,
                                             const int* __restrict__ ei,
                                             const int* __restrict__ ety,
                                             const float* __restrict__ ncs,
                                             float* __restrict__ we,
                                             int* __restrict__ cnt) {
  const int e = (int)((blockIdx.x * 256 + threadIdx.x) >> 4);
  const int sub = threadIdx.x & 15;
  const int s = ei[e], d = ei[EE + e];
  const uint4* rs = (const uint4*)(H + (size_t)s * DD);
  const uint4* rd = (const uint4*)(H + (size_t)d * DD);
  float acc = 0.f;
#pragma unroll
  for (int j = 0; j < 3; ++j) acc += dot4(rs[sub + 16 * j], rd[sub + 16 * j]);
#pragma unroll
  for (int m = 1; m < 16; m <<= 1) acc += __shfl_xor(acc, m, 64);
  if (sub == 0) {
    we[e] = acc * invn[s] * invn[d] / ncs[ety[e]];
    atomicAdd(&cnt[d], 1);
  }
}

// single block, 1024 threads: exclusive scan of 32768 degrees
__global__ __launch_bounds__(1024) void k_scan(const int* __restrict__ deg,
                                               int* __restrict__ rp,
                                               int* __restrict__ cur) {
  __shared__ int ps[1024];
  const int t = threadIdx.x;
  const int base = t * 32;
  int loc[32];
  int tot = 0;
#pragma unroll
  for (int j = 0; j < 32; ++j) { loc[j] = tot; tot += deg[base + j]; }
  ps[t] = tot;
  __syncthreads();
  for (int off = 1; off < 1024; off <<= 1) {
    const int v = (t >= off) ? ps[t - off] : 0;
    __syncthreads();
    ps[t] += v;
    __syncthreads();
  }
  const int myoff = ps[t] - tot;  // exclusive
#pragma unroll
  for (int j = 0; j < 32; ++j) {
    const int val = myoff + loc[j];
    rp[base + j] = val;
    cur[base + j] = val;
  }
  if (t == 1023) rp[NN] = EE;
}

__global__ void k_scatter(const int* __restrict__ ei, const int* __restrict__ etype,
                          const float* __restrict__ we, int* __restrict__ cur,
                          int* __restrict__ epack, float* __restrict__ wsort) {
  const int e = blockIdx.x * 256 + threadIdx.x;
  const int d = ei[EE + e];
  const int pos = atomicAdd(&cur[d], 1);
  epack[pos] = ei[e] | (etype[e] << 16);
  wsort[pos] = we[e];
}

// ---- half lin-GEMM: lin[NN][1536] = H[NN][384] @ BtH[1536][384]^T ----
// BtH = W3T + half*1536*384. R10 structure; NT=12 col tiles, XCD-grouped.
__global__ __launch_bounds__(256) void k_gemm_lin(
    const u16* __restrict__ A, const u16* __restrict__ BtH,
    u16* __restrict__ lin) {
  constexpr int K = DD;        // 384
  constexpr int NT = 12;       // 1536/128
  __shared__ __align__(16) u16 As[128 * 64];
  __shared__ __align__(16) u16 Bs[128 * 64];
  const int tid = threadIdx.x;
  const int w = tid >> 6, l = tid & 63;
  const int per = gridDim.x >> 3;
  const int rpx = per / NT;
  const int xcd = blockIdx.x & 7;
  const int idx = blockIdx.x >> 3;
  const int mb = (xcd * rpx + idx / NT) * 128;
  const int nb = (idx % NT) * 128;
  const int wr = (w >> 1) * 64;
  const int wc = (w & 1) * 64;
  const int sr = tid >> 3;
  const int swz16 = ((l & 7) ^ (l >> 3)) * 8;
  const int lr = l & 15;
  const int cb = l >> 4;
  const int sx = l & 7;
  char* asb = (char*)As;
  char* bsb = (char*)Bs;
  const int wb = w * 1024;
  f32x4 acc[4][4] = {};
  const u16* a0 = A + (size_t)(mb + sr) * K + swz16;
  const u16* b0 = BtH + (size_t)(nb + sr) * K + swz16;
  const size_t r32 = (size_t)32 * K;
  for (int k0 = 0; k0 < K; k0 += 64) {
    gl16(a0 + k0,           asb + wb);
    gl16(a0 + k0 + r32,     asb + wb + 4096);
    gl16(a0 + k0 + 2 * r32, asb + wb + 8192);
    gl16(a0 + k0 + 3 * r32, asb + wb + 12288);
    gl16(b0 + k0,           bsb + wb);
    gl16(b0 + k0 + r32,     bsb + wb + 4096);
    gl16(b0 + k0 + 2 * r32, bsb + wb + 8192);
    gl16(b0 + k0 + 3 * r32, bsb + wb + 12288);
    __syncthreads();
#pragma unroll
    for (int kk = 0; kk < 64; kk += 32) {
      const int cs = (((kk >> 3) + cb) ^ sx) << 4;
      bf16x8 af[4], bfr[4];
#pragma unroll
      for (int m = 0; m < 4; ++m)
        af[m] = *(const bf16x8*)((const char*)As + (wr + m * 16 + lr) * 128 + cs);
#pragma unroll
      for (int n = 0; n < 4; ++n)
        bfr[n] = *(const bf16x8*)((const char*)Bs + (wc + n * 16 + lr) * 128 + cs);
#pragma unroll
      for (int m = 0; m < 4; ++m)
#pragma unroll
        for (int n = 0; n < 4; ++n)
          acc[m][n] = __builtin_amdgcn_mfma_f32_16x16x32_bf16(af[m], bfr[n], acc[m][n], 0, 0, 0);
    }
    __syncthreads();
  }
  const int lg = l >> 4;
#pragma unroll
  for (int n = 0; n < 4; ++n) {
    const int col = nb + wc + n * 16 + lr;
#pragma unroll
    for (int m = 0; m < 4; ++m) {
#pragma unroll
      for (int q = 0; q < 4; ++q) {
        const int row = mb + wr + m * 16 + lg * 4 + q;
        lin[(size_t)row * LHALF + col] = f2bf(acc[m][n][q]);
      }
    }
  }
}

// ---- half edge pass over lin (wave-per-node, 4x unroll) ----
// PASS 0 (ty 0-3): H2acc[i][c] = sum w*lin[src][ty*384+c] + sum_{r<4} s_r*brel[r][c]
// PASS 1 (ty 4-7): H2[i][c] = bf16(relu(H2acc + own sums + sum_{r>=4} s_r*brel[r][c]))
#define EH_BODY(PK, W)                                                        \
  {                                                                           \
    const int ty_ = (PK) >> 16;                                               \
    if (PASS == 0 ? (ty_ < 4) : (ty_ >= 4)) {                                 \
      const int tl_ = PASS == 0 ? ty_ : ty_ - 4;                              \
      const int src_ = (PK) & 0xffff;                                         \
      const u32* r_ = (const u32*)(lin + (size_t)src_ * LHALF + tl_ * DD) + 3 * l; \
      const u32 x0_ = r_[0], x1_ = r_[1], x2_ = r_[2];                        \
      float2 p_;                                                              \
      p_ = up2(x0_); a0 += (W) * p_.x; a1 += (W) * p_.y;                      \
      p_ = up2(x1_); a2 += (W) * p_.x; a3 += (W) * p_.y;                      \
      p_ = up2(x2_); a4 += (W) * p_.x; a5 += (W) * p_.y;                      \
      switch (tl_) {                                                          \
        case 0: s0 += (W); break; case 1: s1 += (W); break;                   \
        case 2: s2 += (W); break; default: s3 += (W); break;                  \
      }                                                                       \
    }                                                                         \
  }

template <int PASS>
__global__ __launch_bounds__(256) void k_edge_half(
    const u16* __restrict__ lin, const int* __restrict__ rp,
    const int* __restrict__ epack, const float* __restrict__ wsort,
    const float* __restrict__ brel, float* __restrict__ H2acc,
    u16* __restrict__ H2) {
  const int i = blockIdx.x * 4 + (threadIdx.x >> 6);
  const int l = threadIdx.x & 63;
  const int e0 = rp[i], e1 = rp[i + 1];
  float a0 = 0, a1 = 0, a2 = 0, a3 = 0, a4 = 0, a5 = 0;
  float s0 = 0, s1 = 0, s2 = 0, s3 = 0;
  int e = e0;
  for (; e + 4 <= e1; e += 4) {
    int pk[4]; float wv[4];
#pragma unroll
    for (int j = 0; j < 4; ++j) { pk[j] = epack[e + j]; wv[j] = wsort[e + j]; }
#pragma unroll
    for (int j = 0; j < 4; ++j) EH_BODY(pk[j], wv[j])
  }
  for (; e < e1; ++e) {
    const int pk = epack[e];
    const float w = wsort[e];
    EH_BODY(pk, w)
  }
  // bias for this pass's 4 relations (redundant per lane; no LDS)
  const float* bp = brel + (PASS * 4) * DD + 6 * l;
  float b0 = 0, b1 = 0, b2 = 0, b3 = 0, b4 = 0, b5 = 0;
#pragma unroll
  for (int r = 0; r < 4; ++r) {
    const float sr = (r == 0) ? s0 : (r == 1) ? s1 : (r == 2) ? s2 : s3;
    const float* bq = bp + r * DD;
    b0 += sr * bq[0]; b1 += sr * bq[1]; b2 += sr * bq[2];
    b3 += sr * bq[3]; b4 += sr * bq[4]; b5 += sr * bq[5];
  }
  float* acc = H2acc + (size_t)i * DD + 6 * l;
  if (PASS == 0) {
    acc[0] = a0 + b0; acc[1] = a1 + b1; acc[2] = a2 + b2;
    acc[3] = a3 + b3; acc[4] = a4 + b4; acc[5] = a5 + b5;
  } else {
    const float t0 = fmaxf(acc[0] + a0 + b0, 0.f);
    const float t1 = fmaxf(acc[1] + a1 + b1, 0.f);
    const float t2 = fmaxf(acc[2] + a2 + b2, 0.f);
    const float t3 = fmaxf(acc[3] + a3 + b3, 0.f);
    const float t4 = fmaxf(acc[4] + a4 + b4, 0.f);
    const float t5 = fmaxf(acc[5] + a5 + b5, 0.f);
    u32* o = (u32*)(H2 + (size_t)i * DD + 6 * l);
    o[0] = pk2(t0, t1);
    o[1] = pk2(t2, t3);
    o[2] = pk2(t4, t5);
  }
}

// ---- unweighted gather-sum (wave-per-node, 4x unroll): smp[i] = sum_e H2[src] ----
#define ES_BODY(SRC)                                                          \
  {                                                                           \
    const u32* r_ = (const u32*)(H2 + (size_t)(SRC) * DD) + 3 * l;            \
    const u32 x0_ = r_[0], x1_ = r_[1], x2_ = r_[2];                          \
    float2 p_;                                                                \
    p_ = up2(x0_); a0 += p_.x; a1 += p_.y;                                    \
    p_ = up2(x1_); a2 += p_.x; a3 += p_.y;                                    \
    p_ = up2(x2_); a4 += p_.x; a5 += p_.y;                                    \
  }

__global__ __launch_bounds__(256) void k_edge_sum(
    const u16* __restrict__ H2, const int* __restrict__ rp,
    const int* __restrict__ epack, u16* __restrict__ smp) {
  const int i = blockIdx.x * 4 + (threadIdx.x >> 6);
  const int l = threadIdx.x & 63;
  const int e0 = rp[i], e1 = rp[i + 1];
  float a0 = 0, a1 = 0, a2 = 0, a3 = 0, a4 = 0, a5 = 0;
  int e = e0;
  for (; e + 4 <= e1; e += 4) {
    const int sA = epack[e] & 0xffff, sB = epack[e + 1] & 0xffff;
    const int sC = epack[e + 2] & 0xffff, sD = epack[e + 3] & 0xffff;
    ES_BODY(sA) ES_BODY(sB) ES_BODY(sC) ES_BODY(sD)
  }
  for (; e < e1; ++e) {
    const int s = epack[e] & 0xffff;
    ES_BODY(s)
  }
  u32* o = (u32*)(smp + (size_t)i * DD + 6 * l);
  o[0] = pk2(a0, a1);
  o[1] = pk2(a2, a3);
  o[2] = pk2(a4, a5);
}

// ---- mp-GEMM (R10-measured structure): 128x128/4-wave, BK=64, K=768,
// A=[smp | H2] (stride 384, split k=384); o = bf16(relu(C + deg*b_mp + b_self))
__global__ __launch_bounds__(256) void k_gemm_mp(
    const u16* __restrict__ A0, const u16* __restrict__ A1,
    const u16* __restrict__ Bt, u16* __restrict__ o_bf,
    const float* __restrict__ bmp, const float* __restrict__ bself,
    const int* __restrict__ rp) {
  constexpr int K = 768;
  constexpr int AS = DD;
  constexpr int NT = 3;
  __shared__ __align__(16) u16 As[128 * 64];
  __shared__ __align__(16) u16 Bs[128 * 64];
  const int tid = threadIdx.x;
  const int w = tid >> 6, l = tid & 63;
  const int per = gridDim.x >> 3;
  const int rpx = per / NT;
  const int xcd = blockIdx.x & 7;
  const int idx = blockIdx.x >> 3;
  const int mb = (xcd * rpx + idx / NT) * 128;
  const int nb = (idx % NT) * 128;
  const int wr = (w >> 1) * 64;
  const int wc = (w & 1) * 64;
  const int sr = tid >> 3;
  const int swz16 = ((l & 7) ^ (l >> 3)) * 8;
  const int lr = l & 15;
  const int cb = l >> 4;
  const int sx = l & 7;
  char* asb = (char*)As;
  char* bsb = (char*)Bs;
  const int wb = w * 1024;
  f32x4 acc[4][4] = {};
  const u16* b0 = Bt + (size_t)(nb + sr) * K + swz16;
  const size_t br32 = (size_t)32 * K;
  const size_t ar32 = (size_t)32 * AS;
  for (int k0 = 0; k0 < K; k0 += 64) {
    const u16* Ab; int ak;
    if (k0 >= DD) { Ab = A1; ak = k0 - DD; }
    else { Ab = A0; ak = k0; }
    const u16* ap = Ab + (size_t)(mb + sr) * AS + ak + swz16;
    gl16(ap,            asb + wb);
    gl16(ap + ar32,     asb + wb + 4096);
    gl16(ap + 2 * ar32, asb + wb + 8192);
    gl16(ap + 3 * ar32, asb + wb + 12288);
    gl16(b0 + k0,            bsb + wb);
    gl16(b0 + k0 + br32,     bsb + wb + 4096);
    gl16(b0 + k0 + 2 * br32, bsb + wb + 8192);
    gl16(b0 + k0 + 3 * br32, bsb + wb + 12288);
    __syncthreads();
#pragma unroll
    for (int kk = 0; kk < 64; kk += 32) {
      const int cs = (((kk >> 3) + cb) ^ sx) << 4;
      bf16x8 af[4], bfr[4];
#pragma unroll
      for (int m = 0; m < 4; ++m)
        af[m] = *(const bf16x8*)((const char*)As + (wr + m * 16 + lr) * 128 + cs);
#pragma unroll
      for (int n = 0; n < 4; ++n)
        bfr[n] = *(const bf16x8*)((const char*)Bs + (wc + n * 16 + lr) * 128 + cs);
#pragma unroll
      for (int m = 0; m < 4; ++m)
#pragma unroll
        for (int n = 0; n < 4; ++n)
          acc[m][n] = __builtin_amdgcn_mfma_f32_16x16x32_bf16(af[m], bfr[n], acc[m][n], 0, 0, 0);
    }
    __syncthreads();
  }
  const int lg = l >> 4;
#pragma unroll
  for (int n = 0; n < 4; ++n) {
    const int col = nb + wc + n * 16 + lr;
    const float bb = bmp[col];
    const float bs = bself[col];
#pragma unroll
    for (int m = 0; m < 4; ++m) {
#pragma unroll
      for (int q = 0; q < 4; ++q) {
        const int row = mb + wr + m * 16 + lg * 4 + q;
        float v = acc[m][n][q];
        const float deg = (float)(rp[row + 1] - rp[row]);
        v = fmaxf(v + deg * bb + bs, 0.f);
        o_bf[(size_t)row * DD + col] = f2bf(v);
      }
    }
  }
}

// ---- mean over 256 nodes per graph ----
__global__ __launch_bounds__(192) void k_mean(const u16* __restrict__ H,
                                              float* __restrict__ out) {
  const int g = blockIdx.x, t = threadIdx.x;
  float ax = 0.f, ay = 0.f;
  const u16* base = H + (size_t)g * 256 * DD;
  for (int j = 0; j < 256; ++j) {
    const float2 hv = up2(*(const u32*)(base + (size_t)j * DD + 2 * t));
    ax += hv.x; ay += hv.y;
  }
  out[g * DD + 2 * t]     = ax * (1.f / 256.f);
  out[g * DD + 2 * t + 1] = ay * (1.f / 256.f);
}

extern "C" void kernel_launch(void* const* d_in, const int* in_sizes, int n_in,
                              void* d_out, int out_size, void* d_ws, size_t ws_size,
                              hipStream_t stream) {
  const float* x     = (const float*)d_in[0];
  const int*   ei    = (const int*)d_in[1];
  const int*   ety   = (const int*)d_in[2];
  const float* Wrel  = (const float*)d_in[4];
  const float* brel  = (const float*)d_in[5];
  const float* ncs   = (const float*)d_in[6];
  const float* Wmp   = (const float*)d_in[7];
  const float* bmp   = (const float*)d_in[8];
  const float* Wself = (const float*)d_in[9];
  const float* bself = (const float*)d_in[10];
  float* out = (float*)d_out;
  (void)in_sizes; (void)n_in; (void)out_size; (void)ws_size;

  char* ws = (char*)d_ws;
  size_t off = 0;
  auto alloc = [&](size_t bytes) {
    void* p = ws + off;
    off = (off + bytes + 255) & ~(size_t)255;
    return p;
  };
  float* invn  = (float*)alloc((size_t)NN * 4);
  int*   rp    = (int*)alloc(((size_t)NN + 1) * 4);
  int*   cur   = (int*)alloc((size_t)NN * 4);
  float* we    = (float*)alloc((size_t)EE * 4);
  int*   epack = (int*)alloc((size_t)EE * 4);
  float* wsort = (float*)alloc((size_t)EE * 4);
  u16*   W3T   = (u16*)alloc((size_t)NCAT * DD * 2);
  u16*   W2T   = (u16*)alloc((size_t)DD * 768 * 2);
  u16*   H     = (u16*)alloc((size_t)NN * DD * 2);
  u16*   H2    = (u16*)alloc((size_t)NN * DD * 2);
  float* H2acc = (float*)alloc((size_t)NN * DD * 4);   // 48 MB
  u16*   lin   = (u16*)alloc((size_t)NN * LHALF * 2);  // 96 MB (half)
  u16*   smp   = lin;  // lin dead after pass 1; smp written after

  k_invnorm<<<NN / 4, 256, 0, stream>>>(x, invn, H, cur);
  k_prepW<<<(NCAT * DD + DD * 768 + 255) / 256, 256, 0, stream>>>(Wrel, Wmp, Wself, W3T, W2T);
  k_cos<<<EE / 16, 256, 0, stream>>>(H, invn, ei, ety, ncs, we, cur);
  k_scan<<<1, 1024, 0, stream>>>(cur, rp, cur);
  k_scatter<<<EE / 256, 256, 0, stream>>>(ei, ety, we, cur, epack, wsort);

  for (int layer = 0; layer < 2; ++layer) {
    // relation half 0 (types 0-3): GEMM + pass 0 (writes f32 partials)
    k_gemm_lin<<<12 * NN / 128, 256, 0, stream>>>(H, W3T, lin);
    k_edge_half<0><<<NN / 4, 256, 0, stream>>>(lin, rp, epack, wsort, brel, H2acc, nullptr);
    // relation half 1 (types 4-7): GEMM + pass 1 (finalize H2)
    k_gemm_lin<<<12 * NN / 128, 256, 0, stream>>>(H, W3T + (size_t)LHALF * DD, lin);
    k_edge_half<1><<<NN / 4, 256, 0, stream>>>(lin, rp, epack, wsort, brel, H2acc, H2);
    // MP phase
    k_edge_sum<<<NN / 4, 256, 0, stream>>>(H2, rp, epack, smp);
    k_gemm_mp<<<3 * NN / 128, 256, 0, stream>>>(smp, H2, W2T, H, bmp, bself, rp);
  }
  k_mean<<<NGR, 192, 0, stream>>>(H, out);
}

// Round 20
// 702.640 us; speedup vs baseline: 1.0576x; 1.0576x over previous
//
#include <hip/hip_runtime.h>
#include <stdint.h>

typedef unsigned short u16;
typedef unsigned int u32;
typedef __attribute__((ext_vector_type(4))) float f32x4;
typedef __attribute__((ext_vector_type(8))) short bf16x8;

#define NN 32768
#define EE 524288
#define DD 384
#define NREL 8
#define NGR 128
#define NCAT (NREL * DD)  // 3072

__device__ __forceinline__ float bf2f(u16 u) {
  union { u32 u; float f; } v; v.u = ((u32)u) << 16; return v.f;
}
__device__ __forceinline__ u16 f2bf(float f) {
  union { float f; u32 u; } v; v.f = f;
  u32 r = v.u + 0x7fffu + ((v.u >> 16) & 1u);
  return (u16)(r >> 16);
}
__device__ __forceinline__ float2 up2(u32 p) {
  return make_float2(bf2f((u16)(p & 0xffffu)), bf2f((u16)(p >> 16)));
}
__device__ __forceinline__ u32 pk2(float a, float b) {
  return (u32)f2bf(a) | ((u32)f2bf(b) << 16);
}
// async 16B global->LDS (LDS dest = wave-uniform base + lane*16)
__device__ __forceinline__ void gl16(const u16* g, char* s) {
  __builtin_amdgcn_global_load_lds(
      (const __attribute__((address_space(1))) unsigned int*)(const void*)g,
      (__attribute__((address_space(3))) unsigned int*)(void*)s, 16, 0, 0);
}
__device__ __forceinline__ float dot4(uint4 a, uint4 b) {
  float2 p, q; float acc;
  p = up2(a.x); q = up2(b.x); acc  = p.x * q.x + p.y * q.y;
  p = up2(a.y); q = up2(b.y); acc += p.x * q.x + p.y * q.y;
  p = up2(a.z); q = up2(b.z); acc += p.x * q.x + p.y * q.y;
  p = up2(a.w); q = up2(b.w); acc += p.x * q.x + p.y * q.y;
  return acc;
}

// ---- per-node: invn = 1/|x|, H = bf16(x) ; zero cur ----
__global__ __launch_bounds__(256) void k_invnorm(const float* __restrict__ x,
                                                 float* __restrict__ invn,
                                                 u16* __restrict__ h0,
                                                 int* __restrict__ cur) {
  const int gid = blockIdx.x * 256 + threadIdx.x;
  if (gid < NN) cur[gid] = 0;
  const int node = gid >> 6;
  const int l = threadIdx.x & 63;
  const float* row = x + (size_t)node * DD;
  float v[6];
  float s = 0.f;
#pragma unroll
  for (int j = 0; j < 6; ++j) { v[j] = row[l + 64 * j]; s += v[j] * v[j]; }
#pragma unroll
  for (int off = 32; off > 0; off >>= 1) s += __shfl_xor(s, off, 64);
  if (l == 0) invn[node] = rsqrtf(s);
  u16* hr = h0 + (size_t)node * DD;
#pragma unroll
  for (int j = 0; j < 6; ++j) hr[l + 64 * j] = f2bf(v[j]);
}

// ---- weight transpose + bf16 convert ----
// W3T[r*384+n][k] (3072 x 384) = W_rel[r][k][n]   (B^T for the lin-GEMM)
// W2T[j][k]       (384 x 768)  = k<384 ? W_mp[k][j] : W_self[k-384][j]
__global__ void k_prepW(const float* __restrict__ Wrel, const float* __restrict__ Wmp,
                        const float* __restrict__ Wself,
                        u16* __restrict__ W3T, u16* __restrict__ W2T) {
  const int i = blockIdx.x * 256 + threadIdx.x;
  const int total1 = NCAT * DD;
  const int total2 = DD * 768;
  if (i < total1) {
    const int ncat = i / DD, k = i % DD;
    const int r = ncat / DD, n = ncat % DD;
    W3T[i] = f2bf(Wrel[(size_t)r * DD * DD + (size_t)k * DD + n]);
  } else if (i < total1 + total2) {
    const int ii = i - total1;
    const int j = ii / 768, k = ii % 768;
    const float v = (k < DD) ? Wmp[k * DD + j] : Wself[(k - DD) * DD + j];
    W2T[ii] = f2bf(v);
  }
}

// ---- degree histogram ----
__global__ void k_hist(const int* __restrict__ ei, int* __restrict__ cnt) {
  const int e = blockIdx.x * 256 + threadIdx.x;
  atomicAdd(&cnt[ei[EE + e]], 1);
}

// single block, 1024 threads: exclusive scan of 32768 degrees
__global__ __launch_bounds__(1024) void k_scan(const int* __restrict__ deg,
                                               int* __restrict__ rp,
                                               int* __restrict__ cur) {
  __shared__ int ps[1024];
  const int t = threadIdx.x;
  const int base = t * 32;
  int loc[32];
  int tot = 0;
#pragma unroll
  for (int j = 0; j < 32; ++j) { loc[j] = tot; tot += deg[base + j]; }
  ps[t] = tot;
  __syncthreads();
  for (int off = 1; off < 1024; off <<= 1) {
    const int v = (t >= off) ? ps[t - off] : 0;
    __syncthreads();
    ps[t] += v;
    __syncthreads();
  }
  const int myoff = ps[t] - tot;  // exclusive
#pragma unroll
  for (int j = 0; j < 32; ++j) {
    const int val = myoff + loc[j];
    rp[base + j] = val;
    cur[base + j] = val;
  }
  if (t == 1023) rp[NN] = EE;
}

// ---- fused cos + scatter: 16 lanes/edge; lane 0 writes sorted slot ----
__global__ __launch_bounds__(256) void k_cos(const u16* __restrict__ H,
                                             const float* __restrict__ invn,
                                             const int* __restrict__ ei,
                                             const int* __restrict__ ety,
                                             const float* __restrict__ ncs,
                                             int* __restrict__ cur,
                                             int* __restrict__ epack,
                                             float* __restrict__ wsort) {
  const int e = (int)((blockIdx.x * 256 + threadIdx.x) >> 4);
  const int sub = threadIdx.x & 15;
  const int s = ei[e], d = ei[EE + e];
  const uint4* rs = (const uint4*)(H + (size_t)s * DD);
  const uint4* rd = (const uint4*)(H + (size_t)d * DD);
  float acc = 0.f;
#pragma unroll
  for (int j = 0; j < 3; ++j) acc += dot4(rs[sub + 16 * j], rd[sub + 16 * j]);
#pragma unroll
  for (int m = 1; m < 16; m <<= 1) acc += __shfl_xor(acc, m, 64);
  if (sub == 0) {
    const int ty = ety[e];
    const float w = acc * invn[s] * invn[d] / ncs[ty];
    const int pos = atomicAdd(&cur[d], 1);
    epack[pos] = s | (ty << 16);
    wsort[pos] = w;
  }
}

// ---- lin-GEMM: lin[NN][3072] = H[NN][384] @ W3T[3072][384]^T ----
__global__ __launch_bounds__(256) void k_gemm_lin(
    const u16* __restrict__ A, const u16* __restrict__ Bt,
    u16* __restrict__ lin) {
  constexpr int K = DD;        // 384
  constexpr int NT = 24;       // 3072/128
  __shared__ __align__(16) u16 As[128 * 64];
  __shared__ __align__(16) u16 Bs[128 * 64];
  const int tid = threadIdx.x;
  const int w = tid >> 6, l = tid & 63;
  const int per = gridDim.x >> 3;
  const int rpx = per / NT;
  const int xcd = blockIdx.x & 7;
  const int idx = blockIdx.x >> 3;
  const int mb = (xcd * rpx + idx / NT) * 128;
  const int nb = (idx % NT) * 128;
  const int wr = (w >> 1) * 64;
  const int wc = (w & 1) * 64;
  const int sr = tid >> 3;
  const int swz16 = ((l & 7) ^ (l >> 3)) * 8;
  const int lr = l & 15;
  const int cb = l >> 4;
  const int sx = l & 7;
  char* asb = (char*)As;
  char* bsb = (char*)Bs;
  const int wb = w * 1024;
  f32x4 acc[4][4] = {};
  const u16* a0 = A + (size_t)(mb + sr) * K + swz16;
  const u16* b0 = Bt + (size_t)(nb + sr) * K + swz16;
  const size_t r32 = (size_t)32 * K;
  for (int k0 = 0; k0 < K; k0 += 64) {
    gl16(a0 + k0,           asb + wb);
    gl16(a0 + k0 + r32,     asb + wb + 4096);
    gl16(a0 + k0 + 2 * r32, asb + wb + 8192);
    gl16(a0 + k0 + 3 * r32, asb + wb + 12288);
    gl16(b0 + k0,           bsb + wb);
    gl16(b0 + k0 + r32,     bsb + wb + 4096);
    gl16(b0 + k0 + 2 * r32, bsb + wb + 8192);
    gl16(b0 + k0 + 3 * r32, bsb + wb + 12288);
    __syncthreads();
#pragma unroll
    for (int kk = 0; kk < 64; kk += 32) {
      const int cs = (((kk >> 3) + cb) ^ sx) << 4;
      bf16x8 af[4], bfr[4];
#pragma unroll
      for (int m = 0; m < 4; ++m)
        af[m] = *(const bf16x8*)((const char*)As + (wr + m * 16 + lr) * 128 + cs);
#pragma unroll
      for (int n = 0; n < 4; ++n)
        bfr[n] = *(const bf16x8*)((const char*)Bs + (wc + n * 16 + lr) * 128 + cs);
#pragma unroll
      for (int m = 0; m < 4; ++m)
#pragma unroll
        for (int n = 0; n < 4; ++n)
          acc[m][n] = __builtin_amdgcn_mfma_f32_16x16x32_bf16(af[m], bfr[n], acc[m][n], 0, 0, 0);
    }
    __syncthreads();
  }
  const int lg = l >> 4;
#pragma unroll
  for (int n = 0; n < 4; ++n) {
    const int col = nb + wc + n * 16 + lr;
#pragma unroll
    for (int m = 0; m < 4; ++m) {
#pragma unroll
      for (int q = 0; q < 4; ++q) {
        const int row = mb + wr + m * 16 + lg * 4 + q;
        lin[(size_t)row * NCAT + col] = f2bf(acc[m][n][q]);
      }
    }
  }
}

// ---- edge aggregation over lin (wave-per-node, 4x edge unroll) ----
#define EL_BODY(PK, W)                                                        \
  {                                                                           \
    const int src_ = (PK) & 0xffff;                                           \
    const int ty_ = (PK) >> 16;                                               \
    const u32* r_ = (const u32*)(lin + (size_t)src_ * NCAT + ty_ * DD) + 3 * l; \
    const u32 x0_ = r_[0], x1_ = r_[1], x2_ = r_[2];                          \
    float2 p_;                                                                \
    p_ = up2(x0_); a0 += (W) * p_.x; a1 += (W) * p_.y;                        \
    p_ = up2(x1_); a2 += (W) * p_.x; a3 += (W) * p_.y;                        \
    p_ = up2(x2_); a4 += (W) * p_.x; a5 += (W) * p_.y;                        \
    switch (ty_) {                                                            \
      case 0: s0 += (W); break; case 1: s1 += (W); break;                     \
      case 2: s2 += (W); break; case 3: s3 += (W); break;                     \
      case 4: s4 += (W); break; case 5: s5 += (W); break;                     \
      case 6: s6 += (W); break; default: s7 += (W); break;                    \
    }                                                                         \
  }

__global__ __launch_bounds__(256) void k_edge_lin(
    const u16* __restrict__ lin, const int* __restrict__ rp,
    const int* __restrict__ epack, const float* __restrict__ wsort,
    const float* __restrict__ brel, u16* __restrict__ H2) {
  const int i = blockIdx.x * 4 + (threadIdx.x >> 6);
  const int l = threadIdx.x & 63;
  const int e0 = rp[i], e1 = rp[i + 1];
  float a0 = 0, a1 = 0, a2 = 0, a3 = 0, a4 = 0, a5 = 0;
  float s0 = 0, s1 = 0, s2 = 0, s3 = 0, s4 = 0, s5 = 0, s6 = 0, s7 = 0;
  int e = e0;
  for (; e + 4 <= e1; e += 4) {
    const int pkA = epack[e], pkB = epack[e + 1], pkC = epack[e + 2], pkD = epack[e + 3];
    const float wA = wsort[e], wB = wsort[e + 1], wC = wsort[e + 2], wD = wsort[e + 3];
    EL_BODY(pkA, wA)
    EL_BODY(pkB, wB)
    EL_BODY(pkC, wC)
    EL_BODY(pkD, wD)
  }
  for (; e < e1; ++e) {
    const int pk = epack[e];
    const float w = wsort[e];
    EL_BODY(pk, w)
  }
  const float* bp = brel + 6 * l;
  float b0 = 0, b1 = 0, b2 = 0, b3 = 0, b4 = 0, b5 = 0;
#pragma unroll
  for (int r = 0; r < 8; ++r) {
    const float sr = (r == 0) ? s0 : (r == 1) ? s1 : (r == 2) ? s2 : (r == 3) ? s3
                   : (r == 4) ? s4 : (r == 5) ? s5 : (r == 6) ? s6 : s7;
    const float* bq = bp + r * DD;
    b0 += sr * bq[0]; b1 += sr * bq[1]; b2 += sr * bq[2];
    b3 += sr * bq[3]; b4 += sr * bq[4]; b5 += sr * bq[5];
  }
  u32* o = (u32*)(H2 + (size_t)i * DD + 6 * l);
  o[0] = pk2(fmaxf(a0 + b0, 0.f), fmaxf(a1 + b1, 0.f));
  o[1] = pk2(fmaxf(a2 + b2, 0.f), fmaxf(a3 + b3, 0.f));
  o[2] = pk2(fmaxf(a4 + b4, 0.f), fmaxf(a5 + b5, 0.f));
}

// ---- unweighted gather-sum (wave-per-node, 4x unroll): smp[i] = sum_e H2[src] ----
#define ES_BODY(SRC)                                                          \
  {                                                                           \
    const u32* r_ = (const u32*)(H2 + (size_t)(SRC) * DD) + 3 * l;            \
    const u32 x0_ = r_[0], x1_ = r_[1], x2_ = r_[2];                          \
    float2 p_;                                                                \
    p_ = up2(x0_); a0 += p_.x; a1 += p_.y;                                    \
    p_ = up2(x1_); a2 += p_.x; a3 += p_.y;                                    \
    p_ = up2(x2_); a4 += p_.x; a5 += p_.y;                                    \
  }

__global__ __launch_bounds__(256) void k_edge_sum(
    const u16* __restrict__ H2, const int* __restrict__ rp,
    const int* __restrict__ epack, u16* __restrict__ smp) {
  const int i = blockIdx.x * 4 + (threadIdx.x >> 6);
  const int l = threadIdx.x & 63;
  const int e0 = rp[i], e1 = rp[i + 1];
  float a0 = 0, a1 = 0, a2 = 0, a3 = 0, a4 = 0, a5 = 0;
  int e = e0;
  for (; e + 4 <= e1; e += 4) {
    const int sA = epack[e] & 0xffff, sB = epack[e + 1] & 0xffff;
    const int sC = epack[e + 2] & 0xffff, sD = epack[e + 3] & 0xffff;
    ES_BODY(sA) ES_BODY(sB) ES_BODY(sC) ES_BODY(sD)
  }
  for (; e < e1; ++e) {
    const int s = epack[e] & 0xffff;
    ES_BODY(s)
  }
  u32* o = (u32*)(smp + (size_t)i * DD + 6 * l);
  o[0] = pk2(a0, a1);
  o[1] = pk2(a2, a3);
  o[2] = pk2(a4, a5);
}

// ---- mp-GEMM (R10-measured structure): 128x128/4-wave, BK=64, K=768,
// A=[smp | H2] (stride 384, split k=384); o = bf16(relu(C + deg*b_mp + b_self))
__global__ __launch_bounds__(256) void k_gemm_mp(
    const u16* __restrict__ A0, const u16* __restrict__ A1,
    const u16* __restrict__ Bt, u16* __restrict__ o_bf,
    const float* __restrict__ bmp, const float* __restrict__ bself,
    const int* __restrict__ rp) {
  constexpr int K = 768;
  constexpr int AS = DD;
  constexpr int NT = 3;
  __shared__ __align__(16) u16 As[128 * 64];
  __shared__ __align__(16) u16 Bs[128 * 64];
  const int tid = threadIdx.x;
  const int w = tid >> 6, l = tid & 63;
  const int per = gridDim.x >> 3;
  const int rpx = per / NT;
  const int xcd = blockIdx.x & 7;
  const int idx = blockIdx.x >> 3;
  const int mb = (xcd * rpx + idx / NT) * 128;
  const int nb = (idx % NT) * 128;
  const int wr = (w >> 1) * 64;
  const int wc = (w & 1) * 64;
  const int sr = tid >> 3;
  const int swz16 = ((l & 7) ^ (l >> 3)) * 8;
  const int lr = l & 15;
  const int cb = l >> 4;
  const int sx = l & 7;
  char* asb = (char*)As;
  char* bsb = (char*)Bs;
  const int wb = w * 1024;
  f32x4 acc[4][4] = {};
  const u16* b0 = Bt + (size_t)(nb + sr) * K + swz16;
  const size_t br32 = (size_t)32 * K;
  const size_t ar32 = (size_t)32 * AS;
  for (int k0 = 0; k0 < K; k0 += 64) {
    const u16* Ab; int ak;
    if (k0 >= DD) { Ab = A1; ak = k0 - DD; }
    else { Ab = A0; ak = k0; }
    const u16* ap = Ab + (size_t)(mb + sr) * AS + ak + swz16;
    gl16(ap,            asb + wb);
    gl16(ap + ar32,     asb + wb + 4096);
    gl16(ap + 2 * ar32, asb + wb + 8192);
    gl16(ap + 3 * ar32, asb + wb + 12288);
    gl16(b0 + k0,            bsb + wb);
    gl16(b0 + k0 + br32,     bsb + wb + 4096);
    gl16(b0 + k0 + 2 * br32, bsb + wb + 8192);
    gl16(b0 + k0 + 3 * br32, bsb + wb + 12288);
    __syncthreads();
#pragma unroll
    for (int kk = 0; kk < 64; kk += 32) {
      const int cs = (((kk >> 3) + cb) ^ sx) << 4;
      bf16x8 af[4], bfr[4];
#pragma unroll
      for (int m = 0; m < 4; ++m)
        af[m] = *(const bf16x8*)((const char*)As + (wr + m * 16 + lr) * 128 + cs);
#pragma unroll
      for (int n = 0; n < 4; ++n)
        bfr[n] = *(const bf16x8*)((const char*)Bs + (wc + n * 16 + lr) * 128 + cs);
#pragma unroll
      for (int m = 0; m < 4; ++m)
#pragma unroll
        for (int n = 0; n < 4; ++n)
          acc[m][n] = __builtin_amdgcn_mfma_f32_16x16x32_bf16(af[m], bfr[n], acc[m][n], 0, 0, 0);
    }
    __syncthreads();
  }
  const int lg = l >> 4;
#pragma unroll
  for (int n = 0; n < 4; ++n) {
    const int col = nb + wc + n * 16 + lr;
    const float bb = bmp[col];
    const float bs = bself[col];
#pragma unroll
    for (int m = 0; m < 4; ++m) {
#pragma unroll
      for (int q = 0; q < 4; ++q) {
        const int row = mb + wr + m * 16 + lg * 4 + q;
        float v = acc[m][n][q];
        const float deg = (float)(rp[row + 1] - rp[row]);
        v = fmaxf(v + deg * bb + bs, 0.f);
        o_bf[(size_t)row * DD + col] = f2bf(v);
      }
    }
  }
}

// ---- mean over 256 nodes per graph ----
__global__ __launch_bounds__(192) void k_mean(const u16* __restrict__ H,
                                              float* __restrict__ out) {
  const int g = blockIdx.x, t = threadIdx.x;
  float ax = 0.f, ay = 0.f;
  const u16* base = H + (size_t)g * 256 * DD;
  for (int j = 0; j < 256; ++j) {
    const float2 hv = up2(*(const u32*)(base + (size_t)j * DD + 2 * t));
    ax += hv.x; ay += hv.y;
  }
  out[g * DD + 2 * t]     = ax * (1.f / 256.f);
  out[g * DD + 2 * t + 1] = ay * (1.f / 256.f);
}

extern "C" void kernel_launch(void* const* d_in, const int* in_sizes, int n_in,
                              void* d_out, int out_size, void* d_ws, size_t ws_size,
                              hipStream_t stream) {
  const float* x     = (const float*)d_in[0];
  const int*   ei    = (const int*)d_in[1];
  const int*   ety   = (const int*)d_in[2];
  const float* Wrel  = (const float*)d_in[4];
  const float* brel  = (const float*)d_in[5];
  const float* ncs   = (const float*)d_in[6];
  const float* Wmp   = (const float*)d_in[7];
  const float* bmp   = (const float*)d_in[8];
  const float* Wself = (const float*)d_in[9];
  const float* bself = (const float*)d_in[10];
  float* out = (float*)d_out;
  (void)in_sizes; (void)n_in; (void)out_size; (void)ws_size;

  char* ws = (char*)d_ws;
  size_t off = 0;
  auto alloc = [&](size_t bytes) {
    void* p = ws + off;
    off = (off + bytes + 255) & ~(size_t)255;
    return p;
  };
  float* invn  = (float*)alloc((size_t)NN * 4);
  int*   rp    = (int*)alloc(((size_t)NN + 1) * 4);
  int*   cur   = (int*)alloc((size_t)NN * 4);
  int*   epack = (int*)alloc((size_t)EE * 4);
  float* wsort = (float*)alloc((size_t)EE * 4);
  u16*   W3T   = (u16*)alloc((size_t)NCAT * DD * 2);
  u16*   W2T   = (u16*)alloc((size_t)DD * 768 * 2);
  u16*   H     = (u16*)alloc((size_t)NN * DD * 2);
  u16*   H2    = (u16*)alloc((size_t)NN * DD * 2);
  u16*   lin   = (u16*)alloc((size_t)NN * NCAT * 2);   // 192 MB
  u16*   smp   = lin;  // lin dead after k_edge_lin; smp written after

  k_invnorm<<<NN / 4, 256, 0, stream>>>(x, invn, H, cur);
  k_prepW<<<(NCAT * DD + DD * 768 + 255) / 256, 256, 0, stream>>>(Wrel, Wmp, Wself, W3T, W2T);
  k_hist<<<EE / 256, 256, 0, stream>>>(ei, cur);
  k_scan<<<1, 1024, 0, stream>>>(cur, rp, cur);
  k_cos<<<EE / 16, 256, 0, stream>>>(H, invn, ei, ety, ncs, cur, epack, wsort);

  for (int layer = 0; layer < 2; ++layer) {
    k_gemm_lin<<<24 * NN / 128, 256, 0, stream>>>(H, W3T, lin);
    k_edge_lin<<<NN / 4, 256, 0, stream>>>(lin, rp, epack, wsort, brel, H2);
    k_edge_sum<<<NN / 4, 256, 0, stream>>>(H2, rp, epack, smp);
    k_gemm_mp<<<3 * NN / 128, 256, 0, stream>>>(smp, H2, W2T, H, bmp, bself, rp);
  }
  k_mean<<<NGR, 192, 0, stream>>>(H, out);
}